// Round 5
// baseline (260.057 us; speedup 1.0000x reference)
//
#include <hip/hip_runtime.h>

#define D_CH   1024
#define L_SEQ  8192
#define NCH    32                       /* channels per block (k2, 1ch/thread) */
#define W_N    3.8349519697141029e-4f   /* 2*pi/16384 */
#define W128A  4.90873852123405e-2f     /* 2*pi/128 */

// ---------------- bf16 pack/unpack --------------------------------------
__device__ __forceinline__ float bf2f(unsigned v){
  union { float f; unsigned u; } x; x.u = v << 16;
  return x.f;
}
// single-instruction RNE pack of (r,i) -> bf16|bf16<<16 (no builtin on gfx950)
__device__ __forceinline__ unsigned packc(float r, float i){
  unsigned u;
  asm("v_cvt_pk_bf16_f32 %0, %1, %2" : "=v"(u) : "v"(r), "v"(i));
  return u;
}
__device__ __forceinline__ float2 upk(unsigned u){
  return make_float2(bf2f(u & 0xffffu), bf2f(u >> 16));
}
// two packed complexes (channels A,B) -> float4 (Are,Aim,Bre,Bim)
__device__ __forceinline__ float4 upk2(uint2 u){
  return make_float4(bf2f(u.x & 0xffffu), bf2f(u.x >> 16),
                     bf2f(u.y & 0xffffu), bf2f(u.y >> 16));
}
// complex multiply both halves of a float4 by (cs + i*sn)
__device__ __forceinline__ float4 cmul2(float4 a, float cs, float sn){
  return make_float4(a.x*cs - a.y*sn, a.x*sn + a.y*cs,
                     a.z*cs - a.w*sn, a.z*sn + a.w*cs);
}

// Diagonal-sheared index into the intermediate arrays (r1/r2).
// Element (row, d) -> row*1024 + ((d + sm*row) & 1023). sm even keeps
// uint2 (2-element) accesses contiguous; sm=0 disables (fallback path).
__device__ __forceinline__ size_t sidx(int row, int d, int sm){
  return (size_t)row * D_CH + (unsigned)((d + row*sm) & (D_CH-1));
}

__device__ __host__ constexpr int bitrev4(int j){
  return ((j&1)<<3)|((j&2)<<1)|((j&4)>>1)|((j&8)>>3);
}
__device__ __host__ constexpr int bitrev3(int j){
  return ((j&1)<<2)|(j&2)|((j&4)>>2);
}

// ---------------- float2 (1 channel) DFT kernels (k2) -------------------
template<int SGN>
__device__ __forceinline__ void dft16(float2* x){
  const float TC[8] = {1.f, 0.9238795325f, 0.7071067812f, 0.3826834324f,
                       0.f, -0.3826834324f, -0.7071067812f, -0.9238795325f};
  const float TS[8] = {0.f, -0.3826834324f, -0.7071067812f, -0.9238795325f,
                       -1.f, -0.9238795325f, -0.7071067812f, -0.3826834324f};
#pragma unroll
  for (int len = 16; len >= 2; len >>= 1){
    const int half = len >> 1, tstep = 16 / len;
#pragma unroll
    for (int st = 0; st < 16; st += len){
#pragma unroll
      for (int j = 0; j < half; j++){
        const float wr = TC[j*tstep];
        const float wi = (SGN > 0) ? TS[j*tstep] : -TS[j*tstep];
        const int a = st + j, b = a + half;
        const float ur = x[a].x, ui = x[a].y;
        const float vr = x[b].x, vi = x[b].y;
        x[a].x = ur + vr; x[a].y = ui + vi;
        const float dr = ur - vr, di = ui - vi;
        x[b].x = dr*wr - di*wi;
        x[b].y = dr*wi + di*wr;
      }
    }
  }
}

template<int SGN>
__device__ __forceinline__ void dft8(float2* x){
  const float TC[4] = {1.f, 0.7071067812f, 0.f, -0.7071067812f};
  const float TS[4] = {0.f, -0.7071067812f, -1.f, -0.7071067812f};
#pragma unroll
  for (int len = 8; len >= 2; len >>= 1){
    const int half = len >> 1, tstep = 8 / len;
#pragma unroll
    for (int st = 0; st < 8; st += len){
#pragma unroll
      for (int j = 0; j < half; j++){
        const float wr = TC[j*tstep];
        const float wi = (SGN > 0) ? TS[j*tstep] : -TS[j*tstep];
        const int a = st + j, b = a + half;
        const float ur = x[a].x, ui = x[a].y;
        const float vr = x[b].x, vi = x[b].y;
        x[a].x = ur + vr; x[a].y = ui + vi;
        const float dr = ur - vr, di = ui - vi;
        x[b].x = dr*wr - di*wi;
        x[b].y = dr*wi + di*wr;
      }
    }
  }
}

// ---------------- float4 (2 channels) DFT kernels (k1/k3) ---------------
template<int SGN>
__device__ __forceinline__ void dft16v4(float4* x){
  const float TC[8] = {1.f, 0.9238795325f, 0.7071067812f, 0.3826834324f,
                       0.f, -0.3826834324f, -0.7071067812f, -0.9238795325f};
  const float TS[8] = {0.f, -0.3826834324f, -0.7071067812f, -0.9238795325f,
                       -1.f, -0.9238795325f, -0.7071067812f, -0.3826834324f};
#pragma unroll
  for (int len = 16; len >= 2; len >>= 1){
    const int half = len >> 1, tstep = 16 / len;
#pragma unroll
    for (int st = 0; st < 16; st += len){
#pragma unroll
      for (int j = 0; j < half; j++){
        const float wr = TC[j*tstep];
        const float wi = (SGN > 0) ? TS[j*tstep] : -TS[j*tstep];
        const int a = st + j, b = a + half;
        const float4 u = x[a], v = x[b];
        x[a] = make_float4(u.x+v.x, u.y+v.y, u.z+v.z, u.w+v.w);
        const float4 dd = make_float4(u.x-v.x, u.y-v.y, u.z-v.z, u.w-v.w);
        x[b] = make_float4(dd.x*wr - dd.y*wi, dd.x*wi + dd.y*wr,
                           dd.z*wr - dd.w*wi, dd.z*wi + dd.w*wr);
      }
    }
  }
}

template<int SGN>
__device__ __forceinline__ void dft8v4(float4* x){
  const float TC[4] = {1.f, 0.7071067812f, 0.f, -0.7071067812f};
  const float TS[4] = {0.f, -0.7071067812f, -1.f, -0.7071067812f};
#pragma unroll
  for (int len = 8; len >= 2; len >>= 1){
    const int half = len >> 1, tstep = 8 / len;
#pragma unroll
    for (int st = 0; st < 8; st += len){
#pragma unroll
      for (int j = 0; j < half; j++){
        const float wr = TC[j*tstep];
        const float wi = (SGN > 0) ? TS[j*tstep] : -TS[j*tstep];
        const int a = st + j, b = a + half;
        const float4 u = x[a], v = x[b];
        x[a] = make_float4(u.x+v.x, u.y+v.y, u.z+v.z, u.w+v.w);
        const float4 dd = make_float4(u.x-v.x, u.y-v.y, u.z-v.z, u.w-v.w);
        x[b] = make_float4(dd.x*wr - dd.y*wi, dd.x*wi + dd.y*wr,
                           dd.z*wr - dd.w*wi, dd.z*wi + dd.w*wr);
      }
    }
  }
}

// Per-block twiddle table for fft128: twF[p*16+k] = e^{-i*2pi*p*k/128}.
__device__ __forceinline__ void build_twF(float2* twF, int tid){
  if (tid < 128){
    const int pp = tid >> 4, kk = tid & 15;
    float sn, cs;
    __sincosf(-W128A * (float)(pp * kk), &sn, &cs);
    twF[tid] = make_float2(cs, sn);
  }
}

// ---- 1-channel fft128 (k2): LDS float2[64*NCH] = 16 KiB ---------------
template<int SGN>
__device__ __forceinline__ void fft128(float2* v, float2* lds,
                                       const float2* twF, int ch, int p){
  dft16<SGN>(v);
#pragma unroll
  for (int slot = 0; slot < 8; slot++){
    const int r = bitrev3(slot);
    const float2 t = twF[p*16 + 2*r];
    const float cs = t.x;
    const float sn = (SGN > 0) ? t.y : -t.y;
    const float2 a = v[slot];
    lds[(p*8 + r)*NCH + ch] = make_float2(a.x*cs - a.y*sn, a.x*sn + a.y*cs);
  }
  __syncthreads();
  float2 t8[8];
#pragma unroll
  for (int pp = 0; pp < 8; pp++) t8[pp] = lds[(pp*8 + p)*NCH + ch]; // s=2p
  dft8<SGN>(t8);
#pragma unroll
  for (int t = 0; t < 8; t++) v[t] = t8[t];
  __syncthreads();
#pragma unroll
  for (int slot = 8; slot < 16; slot++){
    const int r = bitrev3(slot - 8);
    const float2 t = twF[p*16 + 2*r + 1];
    const float cs = t.x;
    const float sn = (SGN > 0) ? t.y : -t.y;
    const float2 a = v[slot];
    lds[(p*8 + r)*NCH + ch] = make_float2(a.x*cs - a.y*sn, a.x*sn + a.y*cs);
  }
  __syncthreads();
#pragma unroll
  for (int pp = 0; pp < 8; pp++) t8[pp] = lds[(pp*8 + p)*NCH + ch]; // s=2p+1
  dft8<SGN>(t8);
#pragma unroll
  for (int t = 0; t < 8; t++) v[8 + t] = t8[t];
}

// ---- 2-channel fft128 (k1/k3): LDS float4[64*32] = 32 KiB --------------
template<int SGN>
__device__ __forceinline__ void fft128v4(float4* v, float4* lds4,
                                         const float2* twF, int ch, int p){
  dft16v4<SGN>(v);
#pragma unroll
  for (int slot = 0; slot < 8; slot++){
    const int r = bitrev3(slot);
    const float2 t = twF[p*16 + 2*r];
    const float cs = t.x;
    const float sn = (SGN > 0) ? t.y : -t.y;
    lds4[(p*8 + r)*32 + ch] = cmul2(v[slot], cs, sn);
  }
  __syncthreads();
  float4 t8[8];
#pragma unroll
  for (int pp = 0; pp < 8; pp++) t8[pp] = lds4[(pp*8 + p)*32 + ch]; // s=2p
  dft8v4<SGN>(t8);
#pragma unroll
  for (int t = 0; t < 8; t++) v[t] = t8[t];
  __syncthreads();
#pragma unroll
  for (int slot = 8; slot < 16; slot++){
    const int r = bitrev3(slot - 8);
    const float2 t = twF[p*16 + 2*r + 1];
    const float cs = t.x;
    const float sn = (SGN > 0) ? t.y : -t.y;
    lds4[(p*8 + r)*32 + ch] = cmul2(v[slot], cs, sn);
  }
  __syncthreads();
#pragma unroll
  for (int pp = 0; pp < 8; pp++) t8[pp] = lds4[(pp*8 + p)*32 + ch]; // s=2p+1
  dft8v4<SGN>(t8);
#pragma unroll
  for (int t = 0; t < 8; t++) v[8 + t] = t8[t];
}

// ---------------------------------------------------------------------------
// K1: forward step1 over n1 (64 nonzero of 128, zero-padded). 2 ch/thread.
// blockIdx.x = dg (fast axis for cross-block row contiguity), .y = n2.
// ---------------------------------------------------------------------------
__global__ __launch_bounds__(256, 4)
void k1_step1(const float* __restrict__ x, const float* __restrict__ h,
              unsigned* __restrict__ Az, unsigned* __restrict__ Ah, int sm){
  __shared__ float4 lds4[64*32];
  __shared__ float2 twF[128];
  __shared__ float2 twO[128];
  const int dg = blockIdx.x, n2 = blockIdx.y, mode = blockIdx.z;
  const int tid = threadIdx.x;
  const int ch = tid & 31, p = tid >> 5;
  const int d = dg*64 + 2*ch;                    // channel pair (d, d+1)

  build_twF(twF, tid);
  if (tid >= 128 && tid < 256){
    const int k1v = tid - 128;
    float sn, cs;
    __sincosf(-W_N * (float)(k1v * n2), &sn, &cs);   // e^{-i 2pi k1 n2 /16384}
    twO[k1v] = make_float2(cs, sn);
  }

  float4 v[16];
  if (mode == 0){
    const float* x0 = x;
    const float* x1 = x + (size_t)L_SEQ * D_CH;
#pragma unroll
    for (int q = 0; q < 8; q++){
      const size_t off = (size_t)(n2 + 128*(p + 8*q)) * D_CH + d;
      const float2 a = *(const float2*)(x0 + off);
      const float2 b = *(const float2*)(x1 + off);
      v[q] = make_float4(a.x, b.x, a.y, b.y);
    }
  } else {
#pragma unroll
    for (int q = 0; q < 8; q++){
      const size_t off = (size_t)(n2 + 128*(p + 8*q)) * D_CH + d;
      const float2 a = *(const float2*)(h + off);
      v[q] = make_float4(a.x, 0.f, a.y, 0.f);
    }
  }
#pragma unroll
  for (int q = 8; q < 16; q++) v[q] = make_float4(0.f, 0.f, 0.f, 0.f);

  __syncthreads();                       // twiddle tables visible
  fft128v4<1>(v, lds4, twF, ch, p);

  unsigned* __restrict__ A = mode ? Ah : Az;
#pragma unroll
  for (int c = 0; c < 2; c++){
#pragma unroll
    for (int t = 0; t < 8; t++){
      const int k1v = (2*p + c) + 16*bitrev3(t);
      const float2 w = twO[k1v];
      const float4 r = cmul2(v[c*8 + t], w.x, w.y);
      *(uint2*)&A[sidx(k1v*128 + n2, d, sm)] =
        make_uint2(packc(r.x, r.y), packc(r.z, r.w));
    }
  }
}

// ---------------------------------------------------------------------------
// K2 (fused, 1 ch/thread): forward step2 for h (in-register Hspec) +
// forward step2 for z + pointwise Z*H/16384 + inverse DFT over k2,
// in place on A_z. blockIdx.x = dg (fast axis), .y = k1.
// ---------------------------------------------------------------------------
__global__ __launch_bounds__(256, 4)
void k2_zh(unsigned* __restrict__ Az, const unsigned* __restrict__ Ah, int sm){
  __shared__ float2 lds[64*NCH];
  __shared__ float2 twF[128];
  const int dg = blockIdx.x, k1 = blockIdx.y;
  const int tid = threadIdx.x;
  const int ch = tid & (NCH-1), p = tid >> 5;
  const int d = dg*NCH + ch;

  build_twF(twF, tid);

  unsigned ha[16], za[16];
#pragma unroll
  for (int q = 0; q < 16; q++)
    ha[q] = Ah[sidx(k1*128 + p + 8*q, d, sm)];
#pragma unroll
  for (int q = 0; q < 16; q++)
    za[q] = Az[sidx(k1*128 + p + 8*q, d, sm)];

  __syncthreads();                       // twF visible

  float2 v[16];
#pragma unroll
  for (int q = 0; q < 16; q++) v[q] = upk(ha[q]);
  fft128<1>(v, lds, twF, ch, p);
  unsigned hs[16];
  const float sc = 1.0f / 16384.0f;
#pragma unroll
  for (int i = 0; i < 16; i++) hs[i] = packc(v[i].x * sc, v[i].y * sc);
  __syncthreads();

#pragma unroll
  for (int q = 0; q < 16; q++) v[q] = upk(za[q]);
  fft128<1>(v, lds, twF, ch, p);

#pragma unroll
  for (int i = 0; i < 16; i++){
    const float2 hv = upk(hs[i]);
    const float zr = v[i].x, zi = v[i].y;
    v[i] = make_float2(zr*hv.x - zi*hv.y, zr*hv.y + zi*hv.x);
  }

  __syncthreads();
  float2 w[8];
#pragma unroll
  for (int c = 0; c < 2; c++)
#pragma unroll
    for (int t = 0; t < 8; t += 2){
      const int k2 = (2*p + c) + 16*bitrev3(t);
      lds[k2*NCH + ch] = v[c*8 + t];
    }
  __syncthreads();
#pragma unroll
  for (int q = 0; q < 8; q++) w[q] = lds[(p + 8*q)*NCH + ch];
  __syncthreads();
#pragma unroll
  for (int c = 0; c < 2; c++)
#pragma unroll
    for (int t = 1; t < 8; t += 2){
      const int k2 = (2*p + c) + 16*bitrev3(t) - 64;
      lds[k2*NCH + ch] = v[c*8 + t];
    }
  __syncthreads();
#pragma unroll
  for (int q = 0; q < 8; q++) v[8 + q] = lds[(p + 8*q)*NCH + ch];
  __syncthreads();
#pragma unroll
  for (int q = 0; q < 8; q++) v[q] = w[q];

  fft128<-1>(v, lds, twF, ch, p);

#pragma unroll
  for (int c = 0; c < 2; c++){
#pragma unroll
    for (int t = 0; t < 8; t++){
      const int m2 = (2*p + c) + 16*bitrev3(t);
      const float2 a = v[c*8 + t];
      Az[sidx(k1*128 + m2, d, sm)] = packc(a.x, a.y);
    }
  }
}

// ---------------------------------------------------------------------------
// K3: inverse step2 over k1 + bias + output write. 2 ch/thread.
// blockIdx.x = dg (fast axis), .y = m2.
// ---------------------------------------------------------------------------
__global__ __launch_bounds__(256, 4)
void k3_inv2(const unsigned* __restrict__ Bz, const float* __restrict__ bias,
             float* __restrict__ out, int sm){
  __shared__ float4 lds4[64*32];
  __shared__ float2 twF[128];
  __shared__ float2 twI[128];
  const int dg = blockIdx.x, m2 = blockIdx.y;
  const int tid = threadIdx.x;
  const int ch = tid & 31, p = tid >> 5;
  const int d = dg*64 + 2*ch;
  const float2 bv = *(const float2*)(bias + d);

  build_twF(twF, tid);
  if (tid >= 128 && tid < 256){
    const int k1 = tid - 128;
    float sn, cs;
    __sincosf(W_N * (float)(m2 * k1), &sn, &cs);     // e^{+i 2pi m2 k1 /16384}
    twI[k1] = make_float2(cs, sn);
  }

  uint2 raw[16];
#pragma unroll
  for (int q = 0; q < 16; q++){
    const int k1 = p + 8*q;
    raw[q] = *(const uint2*)&Bz[sidx(k1*128 + m2, d, sm)];
  }

  __syncthreads();                       // tables visible

  float4 v[16];
#pragma unroll
  for (int q = 0; q < 16; q++){
    const float2 w = twI[p + 8*q];
    v[q] = cmul2(upk2(raw[q]), w.x, w.y);
  }

  fft128v4<-1>(v, lds4, twF, ch, p);     // v[c*8+t] at m1=(2p+c)+16*bitrev3(t)

#pragma unroll
  for (int c = 0; c < 2; c++){
#pragma unroll
    for (int t = 0; t < 8; t += 2){      // t even <=> m1 < 64
      const int m1 = (2*p + c) + 16*bitrev3(t);
      const int tseq = m2 + 128*m1;
      const float4 a = v[c*8 + t];
      *(float2*)&out[(size_t)tseq * D_CH + d] =
        make_float2(a.x + bv.x, a.z + bv.y);
      *(float2*)&out[(size_t)(L_SEQ + tseq) * D_CH + d] =
        make_float2(a.y + bv.x, a.w + bv.y);
    }
  }
}

// ---------------------------------------------------------------------------
extern "C" void kernel_launch(void* const* d_in, const int* in_sizes, int n_in,
                              void* d_out, int out_size, void* d_ws, size_t ws_size,
                              hipStream_t stream){
  (void)in_sizes; (void)n_in; (void)out_size;
  const float* x    = (const float*)d_in[0];
  const float* h    = (const float*)d_in[1];
  const float* bias = (const float*)d_in[2];
  float* out = (float*)d_out;

  const size_t REGION = (size_t)128 * 128 * D_CH * sizeof(unsigned); // 64 MiB
  unsigned *r1, *r2;
  int sm;
  if (ws_size >= 2 * REGION){
    r1 = (unsigned*)d_ws;                       // A_z -> b
    r2 = (unsigned*)((char*)d_ws + REGION);     // A_h
    sm = 70;   // diagonal shear on (even, so uint2 accesses stay contiguous)
  } else {
    r1 = (unsigned*)d_out;  // K3 reads each aliased cell before its stores,
    r2 = (unsigned*)d_ws;   //   valid only with sm=0 (d-slices stay disjoint)
    sm = 0;
  }

  const dim3 blk(256, 1, 1);
  hipLaunchKernelGGL(k1_step1, dim3(16,128,2), blk, 0, stream, x, h, r1, r2, sm);
  hipLaunchKernelGGL(k2_zh,    dim3(32,128,1), blk, 0, stream, r1, r2, sm);
  hipLaunchKernelGGL(k3_inv2,  dim3(16,128,1), blk, 0, stream, r1, bias, out, sm);
}

// Round 6
// 232.804 us; speedup vs baseline: 1.1171x; 1.1171x over previous
//
#include <hip/hip_runtime.h>

#define D_CH   1024
#define L_SEQ  8192
#define NCH    32                       /* channels per block */
#define W_N    3.8349519697141029e-4f   /* 2*pi/16384 */
#define W128A  4.90873852123405e-2f     /* 2*pi/128 */

// ---------------- bf16 pack/unpack --------------------------------------
__device__ __forceinline__ float bf2f(unsigned v){
  union { float f; unsigned u; } x; x.u = v << 16;
  return x.f;
}
// single-instruction RNE pack of (r,i) -> bf16|bf16<<16 (no builtin on gfx950)
__device__ __forceinline__ unsigned packc(float r, float i){
  unsigned u;
  asm("v_cvt_pk_bf16_f32 %0, %1, %2" : "=v"(u) : "v"(r), "v"(i));
  return u;
}
__device__ __forceinline__ float2 upk(unsigned u){
  return make_float2(bf2f(u & 0xffffu), bf2f(u >> 16));
}

__device__ __host__ constexpr int bitrev3(int j){
  return ((j&1)<<2)|(j&2)|((j&4)>>2);
}

// 16-pt DIF DFT, natural in; slot j holds X[bitrev4(j)].
template<int SGN>
__device__ __forceinline__ void dft16(float2* x){
  const float TC[8] = {1.f, 0.9238795325f, 0.7071067812f, 0.3826834324f,
                       0.f, -0.3826834324f, -0.7071067812f, -0.9238795325f};
  const float TS[8] = {0.f, -0.3826834324f, -0.7071067812f, -0.9238795325f,
                       -1.f, -0.9238795325f, -0.7071067812f, -0.3826834324f};
#pragma unroll
  for (int len = 16; len >= 2; len >>= 1){
    const int half = len >> 1, tstep = 16 / len;
#pragma unroll
    for (int st = 0; st < 16; st += len){
#pragma unroll
      for (int j = 0; j < half; j++){
        const float wr = TC[j*tstep];
        const float wi = (SGN > 0) ? TS[j*tstep] : -TS[j*tstep];
        const int a = st + j, b = a + half;
        const float ur = x[a].x, ui = x[a].y;
        const float vr = x[b].x, vi = x[b].y;
        x[a].x = ur + vr; x[a].y = ui + vi;
        const float dr = ur - vr, di = ui - vi;
        x[b].x = dr*wr - di*wi;
        x[b].y = dr*wi + di*wr;
      }
    }
  }
}

// dft16 specialized for x[8..15] == 0 (never read); stage-1 butterflies
// collapse to x[j+8] = x[j]*w(j), x[j] unchanged.
template<int SGN>
__device__ __forceinline__ void dft16z(float2* x){
  const float TC[8] = {1.f, 0.9238795325f, 0.7071067812f, 0.3826834324f,
                       0.f, -0.3826834324f, -0.7071067812f, -0.9238795325f};
  const float TS[8] = {0.f, -0.3826834324f, -0.7071067812f, -0.9238795325f,
                       -1.f, -0.9238795325f, -0.7071067812f, -0.3826834324f};
#pragma unroll
  for (int j = 0; j < 8; j++){
    const float wr = TC[j];
    const float wi = (SGN > 0) ? TS[j] : -TS[j];
    const float ur = x[j].x, ui = x[j].y;
    x[j+8].x = ur*wr - ui*wi;
    x[j+8].y = ur*wi + ui*wr;
  }
#pragma unroll
  for (int len = 8; len >= 2; len >>= 1){
    const int half = len >> 1, tstep = 16 / len;
#pragma unroll
    for (int st = 0; st < 16; st += len){
#pragma unroll
      for (int j = 0; j < half; j++){
        const float wr = TC[j*tstep];
        const float wi = (SGN > 0) ? TS[j*tstep] : -TS[j*tstep];
        const int a = st + j, b = a + half;
        const float ur = x[a].x, ui = x[a].y;
        const float vr = x[b].x, vi = x[b].y;
        x[a].x = ur + vr; x[a].y = ui + vi;
        const float dr = ur - vr, di = ui - vi;
        x[b].x = dr*wr - di*wi;
        x[b].y = dr*wi + di*wr;
      }
    }
  }
}

// 8-pt DIF DFT, natural in; slot j holds X[bitrev3(j)].
template<int SGN>
__device__ __forceinline__ void dft8(float2* x){
  const float TC[4] = {1.f, 0.7071067812f, 0.f, -0.7071067812f};
  const float TS[4] = {0.f, -0.7071067812f, -1.f, -0.7071067812f};
#pragma unroll
  for (int len = 8; len >= 2; len >>= 1){
    const int half = len >> 1, tstep = 8 / len;
#pragma unroll
    for (int st = 0; st < 8; st += len){
#pragma unroll
      for (int j = 0; j < half; j++){
        const float wr = TC[j*tstep];
        const float wi = (SGN > 0) ? TS[j*tstep] : -TS[j*tstep];
        const int a = st + j, b = a + half;
        const float ur = x[a].x, ui = x[a].y;
        const float vr = x[b].x, vi = x[b].y;
        x[a].x = ur + vr; x[a].y = ui + vi;
        const float dr = ur - vr, di = ui - vi;
        x[b].x = dr*wr - di*wi;
        x[b].y = dr*wi + di*wr;
      }
    }
  }
}

// Per-block twiddle table for fft128: twF[p*16+k] = e^{-i*2pi*p*k/128}.
__device__ __forceinline__ void build_twF(float2* twF, int tid){
  if (tid < 128){
    const int pp = tid >> 4, kk = tid & 15;
    float sn, cs;
    __sincosf(-W128A * (float)(pp * kk), &sn, &cs);
    twF[tid] = make_float2(cs, sn);
  }
}

// 128-pt DFT across 8 p-threads (p = tid>>5) x NCH channels (ch = tid&31).
// Entry: v[q] = f[p + 8q] (ZT: q<8 only, upper half logically zero).
// Exit: v[c*8+t] = F[(2p+c) + 16*bitrev3(t)].
// LDS buffer: float2[64*NCH] = 16 KiB. 3 internal barriers; caller must
// __syncthreads() before reusing THIS lds buffer afterwards.
template<int SGN, bool ZT>
__device__ __forceinline__ void fft128(float2* v, float2* lds,
                                       const float2* twF, int ch, int p){
  if (ZT) dft16z<SGN>(v); else dft16<SGN>(v);
  // ---- phase 0: slots 0..7 (s = 2r even, r = bitrev3(slot)) ----
#pragma unroll
  for (int slot = 0; slot < 8; slot++){
    const int r = bitrev3(slot);
    const float2 t = twF[p*16 + 2*r];
    const float cs = t.x;
    const float sn = (SGN > 0) ? t.y : -t.y;
    const float2 a = v[slot];
    lds[(p*8 + r)*NCH + ch] = make_float2(a.x*cs - a.y*sn, a.x*sn + a.y*cs);
  }
  __syncthreads();
  float2 t8[8];
#pragma unroll
  for (int pp = 0; pp < 8; pp++) t8[pp] = lds[(pp*8 + p)*NCH + ch]; // s=2p
  dft8<SGN>(t8);
#pragma unroll
  for (int t = 0; t < 8; t++) v[t] = t8[t];
  __syncthreads();                       // reads done before phase-1 stores
  // ---- phase 1: slots 8..15 (s = 2r+1 odd) ----
#pragma unroll
  for (int slot = 8; slot < 16; slot++){
    const int r = bitrev3(slot - 8);
    const float2 t = twF[p*16 + 2*r + 1];
    const float cs = t.x;
    const float sn = (SGN > 0) ? t.y : -t.y;
    const float2 a = v[slot];
    lds[(p*8 + r)*NCH + ch] = make_float2(a.x*cs - a.y*sn, a.x*sn + a.y*cs);
  }
  __syncthreads();
#pragma unroll
  for (int pp = 0; pp < 8; pp++) t8[pp] = lds[(pp*8 + p)*NCH + ch]; // s=2p+1
  dft8<SGN>(t8);
#pragma unroll
  for (int t = 0; t < 8; t++) v[8 + t] = t8[t];
}

// ---------------------------------------------------------------------------
// K1: forward step1 over n1 (64 nonzero of 128, zero-padded).
// A[k1,n2] = w16384^{k1 n2} * DFT128_{n1}(z[n2+128 n1]).
// mode 0: z = x[0] + i x[1]; mode 1: h (real -> only rows k1<=64 stored).
// Software-pipelined: 2 n2-tiles per block, ping-pong LDS; both tiles'
// loads issue up-front, tile-a stores overlap tile-b compute.
// ---------------------------------------------------------------------------
__global__ __launch_bounds__(256, 4)
void k1_step1(const float* __restrict__ x, const float* __restrict__ h,
              unsigned* __restrict__ Az, unsigned* __restrict__ Ah){
  __shared__ float2 ldsA[64*NCH];
  __shared__ float2 ldsB[64*NCH];
  __shared__ float2 twF[128];
  __shared__ float2 twOa[128];
  __shared__ float2 twOb[128];
  const int n2a = blockIdx.x*2, n2b = n2a + 1;
  const int dg = blockIdx.y, mode = blockIdx.z;
  const int tid = threadIdx.x;
  const int ch = tid & (NCH-1), p = tid >> 5;
  const int d = dg*NCH + ch;

  // issue ALL loads for both tiles first (fetch hides under tile-a compute)
  float2 va[16], vb[16];
  if (mode == 0){
    const float* x0 = x;
    const float* x1 = x + (size_t)L_SEQ * D_CH;
#pragma unroll
    for (int q = 0; q < 8; q++){
      const size_t ra = (size_t)(n2a + 128*(p + 8*q)) * D_CH + d;
      const size_t rb = (size_t)(n2b + 128*(p + 8*q)) * D_CH + d;
      va[q] = make_float2(x0[ra], x1[ra]);
      vb[q] = make_float2(x0[rb], x1[rb]);
    }
  } else {
#pragma unroll
    for (int q = 0; q < 8; q++){
      const size_t ra = (size_t)(n2a + 128*(p + 8*q)) * D_CH + d;
      const size_t rb = (size_t)(n2b + 128*(p + 8*q)) * D_CH + d;
      va[q] = make_float2(h[ra], 0.f);
      vb[q] = make_float2(h[rb], 0.f);
    }
  }

  // per-block twiddle tables (<=3 sincos per thread)
  build_twF(twF, tid);
  if (tid >= 128){
    const int k1v = tid - 128;
    float sn, cs;
    __sincosf(-W_N * (float)(k1v * n2a), &sn, &cs);
    twOa[k1v] = make_float2(cs, sn);
    __sincosf(-W_N * (float)(k1v * n2b), &sn, &cs);
    twOb[k1v] = make_float2(cs, sn);
  }
  __syncthreads();                       // tables visible

  unsigned* __restrict__ A = mode ? Ah : Az;

  // ---- tile a ----
  fft128<1, true>(va, ldsA, twF, ch, p);
#pragma unroll
  for (int c = 0; c < 2; c++){
#pragma unroll
    for (int t = 0; t < 8; t++){
      const int k1v = (2*p + c) + 16*bitrev3(t);
      if (mode == 1 && k1v > 64) continue;      // Hermitian: skip mirror rows
      const float2 w = twOa[k1v];
      const float2 a = va[c*8 + t];
      A[((size_t)k1v*128 + n2a)*D_CH + d] =
        packc(a.x*w.x - a.y*w.y, a.x*w.y + a.y*w.x);
    }
  }

  // ---- tile b (different LDS buffer -> no barrier; stores_a in flight) ----
  fft128<1, true>(vb, ldsB, twF, ch, p);
#pragma unroll
  for (int c = 0; c < 2; c++){
#pragma unroll
    for (int t = 0; t < 8; t++){
      const int k1v = (2*p + c) + 16*bitrev3(t);
      if (mode == 1 && k1v > 64) continue;
      const float2 w = twOb[k1v];
      const float2 a = vb[c*8 + t];
      A[((size_t)k1v*128 + n2b)*D_CH + d] =
        packc(a.x*w.x - a.y*w.y, a.x*w.y + a.y*w.x);
    }
  }
}

// ---------------------------------------------------------------------------
// K2 (fused): forward step2 for h (in-register Hspec; mirror-reconstructed
// for k1>64 from Hermitian symmetry) + forward step2 for z + pointwise
// Z*H/16384 + inverse DFT over k2, in place on A_z.
// ---------------------------------------------------------------------------
__global__ __launch_bounds__(256, 4)
void k2_zh(unsigned* __restrict__ Az, const unsigned* __restrict__ Ah){
  __shared__ float2 lds[64*NCH];
  __shared__ float2 twF[128];
  __shared__ float2 tw1[128];            // e^{-2pi i n/128}
  const int k1 = blockIdx.x, dg = blockIdx.y;
  const int tid = threadIdx.x;
  const int ch = tid & (NCH-1), p = tid >> 5;
  const int d = dg*NCH + ch;
  const int k1r = (k1 > 64) ? 128 - k1 : k1;     // Hermitian mirror source
  const size_t basez = (size_t)k1  * 128 * D_CH + d;
  const size_t baseh = (size_t)k1r * 128 * D_CH + d;

  build_twF(twF, tid);
  if (tid < 128){
    float sn, cs;
    __sincosf(-W128A * (float)tid, &sn, &cs);
    tw1[tid] = make_float2(cs, sn);
  }

  // issue all independent loads up front (MLP)
  unsigned ha[16], za[16];
#pragma unroll
  for (int q = 0; q < 16; q++)
    ha[q] = Ah[baseh + (size_t)(p + 8*q) * D_CH];
#pragma unroll
  for (int q = 0; q < 16; q++)
    za[q] = Az[basez + (size_t)(p + 8*q) * D_CH];

  __syncthreads();                       // tables visible

  // ---- H: forward 128-pt over n2, keep spectrum packed in regs ----
  float2 v[16];
  if (k1 <= 64){
#pragma unroll
    for (int q = 0; q < 16; q++) v[q] = upk(ha[q]);
  } else {
    // A_h[k1,n2] = tw1[n2] * conj(A_h[128-k1,n2])
#pragma unroll
    for (int q = 0; q < 16; q++){
      const float2 a = upk(ha[q]);
      const float2 t = tw1[p + 8*q];
      v[q] = make_float2(t.x*a.x + t.y*a.y, t.y*a.x - t.x*a.y);
    }
  }
  fft128<1, false>(v, lds, twF, ch, p);
  unsigned hs[16];
  const float sc = 1.0f / 16384.0f;      // fold ifft scale into Hspec
#pragma unroll
  for (int i = 0; i < 16; i++) hs[i] = packc(v[i].x * sc, v[i].y * sc);
  __syncthreads();                       // lds reads done before z-fft stores

  // ---- Z: forward 128-pt over n2 ----
#pragma unroll
  for (int q = 0; q < 16; q++) v[q] = upk(za[q]);
  fft128<1, false>(v, lds, twF, ch, p);

  // ---- pointwise multiply (orders match) ----
#pragma unroll
  for (int i = 0; i < 16; i++){
    const float2 hv = upk(hs[i]);
    const float zr = v[i].x, zi = v[i].y;
    v[i] = make_float2(zr*hv.x - zi*hv.y, zr*hv.y + zi*hv.x);
  }

  // ---- redistribute to natural k2 order: v[q] = Y[p+8q] ----
  __syncthreads();                       // protect fft128's lds reads
  float2 w[8];
  // phase A: k2 < 64  (t even)
#pragma unroll
  for (int c = 0; c < 2; c++)
#pragma unroll
    for (int t = 0; t < 8; t += 2){
      const int k2 = (2*p + c) + 16*bitrev3(t);
      lds[k2*NCH + ch] = v[c*8 + t];
    }
  __syncthreads();
#pragma unroll
  for (int q = 0; q < 8; q++) w[q] = lds[(p + 8*q)*NCH + ch];
  __syncthreads();
  // phase B: k2 >= 64 (t odd)
#pragma unroll
  for (int c = 0; c < 2; c++)
#pragma unroll
    for (int t = 1; t < 8; t += 2){
      const int k2 = (2*p + c) + 16*bitrev3(t) - 64;
      lds[k2*NCH + ch] = v[c*8 + t];
    }
  __syncthreads();
#pragma unroll
  for (int q = 0; q < 8; q++) v[8 + q] = lds[(p + 8*q)*NCH + ch];
  __syncthreads();                       // reads done before inverse stores
#pragma unroll
  for (int q = 0; q < 8; q++) v[q] = w[q];

  // ---- inverse 128-pt over k2 ----
  fft128<-1, false>(v, lds, twF, ch, p); // v[c*8+t] = b at m2=(2p+c)+16*bitrev3(t)

#pragma unroll
  for (int c = 0; c < 2; c++){
#pragma unroll
    for (int t = 0; t < 8; t++){
      const int m2 = (2*p + c) + 16*bitrev3(t);
      const float2 a = v[c*8 + t];
      Az[basez + (size_t)m2 * D_CH] = packc(a.x, a.y);
    }
  }
}

// ---------------------------------------------------------------------------
// K3: inverse step2 over k1 + bias + output write. Software-pipelined:
// 2 m2-tiles per block, ping-pong LDS; tile-a stores overlap tile-b fft.
// y[0,t,d] = Re(w)+bias, y[1,t,d] = Im(w)+bias, t = m2 + 128*m1, m1 < 64.
// ---------------------------------------------------------------------------
__global__ __launch_bounds__(256, 4)
void k3_inv2(const unsigned* __restrict__ Bz, const float* __restrict__ bias,
             float* __restrict__ out){
  __shared__ float2 ldsA[64*NCH];
  __shared__ float2 ldsB[64*NCH];
  __shared__ float2 twF[128];
  __shared__ float2 twIa[128];
  __shared__ float2 twIb[128];
  const int m2a = blockIdx.x*2, m2b = m2a + 1;
  const int dg = blockIdx.y;
  const int tid = threadIdx.x;
  const int ch = tid & (NCH-1), p = tid >> 5;
  const int d = dg*NCH + ch;
  const float bv = bias[d];

  // issue ALL loads for both tiles first
  unsigned rawa[16], rawb[16];
#pragma unroll
  for (int q = 0; q < 16; q++){
    const int k1 = p + 8*q;
    rawa[q] = Bz[((size_t)k1*128 + m2a) * D_CH + d];
    rawb[q] = Bz[((size_t)k1*128 + m2b) * D_CH + d];
  }

  build_twF(twF, tid);
  if (tid >= 128){
    const int k1 = tid - 128;
    float sn, cs;
    __sincosf(W_N * (float)(m2a * k1), &sn, &cs);    // e^{+2pi i m2 k1 /16384}
    twIa[k1] = make_float2(cs, sn);
    __sincosf(W_N * (float)(m2b * k1), &sn, &cs);
    twIb[k1] = make_float2(cs, sn);
  }
  __syncthreads();                       // tables visible

  float2 v[16];
  // ---- tile a ----
#pragma unroll
  for (int q = 0; q < 16; q++){
    const float2 w = twIa[p + 8*q];
    const float2 a = upk(rawa[q]);
    v[q] = make_float2(a.x*w.x - a.y*w.y, a.x*w.y + a.y*w.x);
  }
  fft128<-1, false>(v, ldsA, twF, ch, p);
#pragma unroll
  for (int c = 0; c < 2; c++){
#pragma unroll
    for (int t = 0; t < 8; t += 2){      // t even <=> bitrev3(t)<4 <=> m1 < 64
      const int m1 = (2*p + c) + 16*bitrev3(t);
      const int tseq = m2a + 128*m1;
      const float2 a = v[c*8 + t];
      out[(size_t)tseq * D_CH + d]            = a.x + bv;
      out[(size_t)(L_SEQ + tseq) * D_CH + d]  = a.y + bv;
    }
  }

  // ---- tile b (different LDS buffer; stores_a in flight) ----
#pragma unroll
  for (int q = 0; q < 16; q++){
    const float2 w = twIb[p + 8*q];
    const float2 a = upk(rawb[q]);
    v[q] = make_float2(a.x*w.x - a.y*w.y, a.x*w.y + a.y*w.x);
  }
  fft128<-1, false>(v, ldsB, twF, ch, p);
#pragma unroll
  for (int c = 0; c < 2; c++){
#pragma unroll
    for (int t = 0; t < 8; t += 2){
      const int m1 = (2*p + c) + 16*bitrev3(t);
      const int tseq = m2b + 128*m1;
      const float2 a = v[c*8 + t];
      out[(size_t)tseq * D_CH + d]            = a.x + bv;
      out[(size_t)(L_SEQ + tseq) * D_CH + d]  = a.y + bv;
    }
  }
}

// ---------------------------------------------------------------------------
extern "C" void kernel_launch(void* const* d_in, const int* in_sizes, int n_in,
                              void* d_out, int out_size, void* d_ws, size_t ws_size,
                              hipStream_t stream){
  (void)in_sizes; (void)n_in; (void)out_size;
  const float* x    = (const float*)d_in[0];
  const float* h    = (const float*)d_in[1];
  const float* bias = (const float*)d_in[2];
  float* out = (float*)d_out;

  const size_t REGION = (size_t)128 * 128 * D_CH * sizeof(unsigned); // 64 MiB
  unsigned *r1, *r2;
  if (ws_size >= 2 * REGION){
    r1 = (unsigned*)d_ws;                       // A_z -> b
    r2 = (unsigned*)((char*)d_ws + REGION);     // A_h (rows k1<=64 used)
  } else {
    r1 = (unsigned*)d_out;  // safe: K3 per-tile reads are row-disjoint from
    r2 = (unsigned*)d_ws;   //   its other tile's writes (m2a != m2b mod 128)
  }

  const dim3 blk(256, 1, 1);
  hipLaunchKernelGGL(k1_step1, dim3(64,32,2), blk, 0, stream, x, h, r1, r2);
  hipLaunchKernelGGL(k2_zh,    dim3(128,32,1), blk, 0, stream, r1, r2);
  hipLaunchKernelGGL(k3_inv2,  dim3(64,32,1), blk, 0, stream, r1, bias, out);
}